// Round 1
// 709.015 us; speedup vs baseline: 1.1340x; 1.1340x over previous
//
#include <hip/hip_runtime.h>
#include <hip/hip_fp16.h>
#include <math.h>

#define NNODES 100000
#define NEDGES 1600000
#define NGRAPH 256
#define NCONV  3
#define TBL    4096
#define CHUNK  512
#define NCHUNK 196         // ceil(100000/512)
#define R_MIN_ 1.0f
#define R_MAX_ 6.0f
#define LOG2E  1.4426950408889634f

typedef float v2f __attribute__((ext_vector_type(2)));

__device__ __forceinline__ float softplus_f(float x){
  return fmaxf(x, 0.f) + __logf(1.f + __expf(-fabsf(x)));
}
__device__ __forceinline__ float sigmoid_f(float x){
  return __builtin_amdgcn_rcpf(1.f + __expf(-x));
}
__device__ __forceinline__ void fma4(float4& a, float s, const float4 w){
  a.x = fmaf(s, w.x, a.x); a.y = fmaf(s, w.y, a.y);
  a.z = fmaf(s, w.z, a.z); a.w = fmaf(s, w.w, a.w);
}

// ---------------- init: zero chunk counters + graph accumulators ----------------
__global__ void k_init(int* ccnt, float* gsum, int* gcnt){
  int i = blockIdx.x*256 + threadIdx.x;
  if (i < 256) ccnt[i] = 0;
  if (i < NGRAPH){ gsum[i] = 0.f; gcnt[i] = 0; }
}

// ---------------- embedding gather ----------------
__global__ void k_embed(const int* __restrict__ numbers, const float* __restrict__ embed,
                        float* __restrict__ x){
  int i = blockIdx.x*256 + threadIdx.x;
  if (i >= NNODES*64) return;
  int n = i >> 6, c = i & 63;
  x[i] = embed[numbers[n]*64 + c];
}

// ---------------- chunk count: LDS histogram then 196 global atomics per block ----------------
__global__ void k_cnt(const int* __restrict__ src, int* ccnt){
  __shared__ int l[NCHUNK];
  int t = threadIdx.x;
  int e0 = blockIdx.x * 2048;
  if (t < NCHUNK) l[t] = 0;
  __syncthreads();
  #pragma unroll
  for (int k = 0; k < 8; k++){
    int e = e0 + k*256 + t;
    if (e < NEDGES) atomicAdd(&l[src[e] / CHUNK], 1);
  }
  __syncthreads();
  if (t < NCHUNK && l[t] > 0) atomicAdd(&ccnt[t], l[t]);
}

// ---------------- chunk scan: cbase prefix, init ccur, sentinel ----------------
__global__ void k_cscan(const int* __restrict__ ccnt, int* __restrict__ cbase,
                        int* __restrict__ ccur, int* __restrict__ offs){
  int t = threadIdx.x;
  if (t == 0){
    int run = 0;
    for (int c = 0; c < NCHUNK; c++){ cbase[c] = run; run += ccnt[c]; }
    cbase[NCHUNK] = NEDGES;
    offs[NNODES] = NEDGES;
  }
  __syncthreads();
  if (t < NCHUNK) ccur[t] = cbase[t];
}

// ---------------- pass 1: bin edges by 512-node chunk ----------------
// staged record: .x = (src&511)<<17 | tgt ; .y = nearest-neighbor table idx
__global__ void k_bin(const int* __restrict__ src, const int* __restrict__ tgt,
                      const float* __restrict__ elen, int* ccur,
                      int2* __restrict__ eb){
  __shared__ int lcnt[NCHUNK];
  __shared__ int lbase[NCHUNK];
  __shared__ int loff[NCHUNK];
  int t = threadIdx.x;
  int e0 = blockIdx.x * 2048;
  if (t < NCHUNK){ lcnt[t] = 0; loff[t] = 0; }
  __syncthreads();
  #pragma unroll
  for (int k = 0; k < 8; k++){
    int e = e0 + k*256 + t;
    if (e < NEDGES) atomicAdd(&lcnt[src[e] / CHUNK], 1);
  }
  __syncthreads();
  if (t < NCHUNK && lcnt[t] > 0) lbase[t] = atomicAdd(&ccur[t], lcnt[t]);
  __syncthreads();
  #pragma unroll
  for (int k = 0; k < 8; k++){
    int e = e0 + k*256 + t;
    if (e < NEDGES){
      int s = src[e];
      int c = s / CHUNK;
      int r = atomicAdd(&loff[c], 1);
      float key = (elen[e] - R_MIN_) * ((float)(TBL-1)/(R_MAX_-R_MIN_));
      key = fmaxf(key, 0.f);
      int idx = (int)(key + 0.5f);
      if (idx > TBL-1) idx = TBL-1;
      eb[lbase[c] + r] = make_int2(((s & (CHUNK-1)) << 17) | tgt[e], idx);
    }
  }
}

// ---------------- pass 2: fine scatter; also builds offs via LDS count+scan ----------------
__global__ void k_fine(const int* __restrict__ cbase, const int2* __restrict__ eb,
                       int2* __restrict__ ep, int* __restrict__ offs){
  __shared__ int lcnt[CHUNK];
  __shared__ int lsc[CHUNK];
  int c = blockIdx.x;
  int t = threadIdx.x;                    // 512 threads
  int n0 = c * CHUNK;
  int n1 = min(n0 + CHUNK, NNODES);
  int cnt = n1 - n0;
  int j0 = cbase[c], j1 = cbase[c+1];
  lcnt[t] = 0;
  __syncthreads();
  for (int e = j0 + t; e < j1; e += 512)
    atomicAdd(&lcnt[((unsigned)eb[e].x) >> 17], 1);
  __syncthreads();
  lsc[t] = lcnt[t];
  __syncthreads();
  for (int d = 1; d < 512; d <<= 1){
    int v = (t >= d) ? lsc[t-d] : 0;
    __syncthreads();
    lsc[t] += v;
    __syncthreads();
  }
  int excl = lsc[t] - lcnt[t];
  if (t < cnt) offs[n0 + t] = j0 + excl;
  __syncthreads();
  lcnt[t] = j0 + excl;                    // reuse as cursors
  __syncthreads();
  for (int e = j0 + t; e < j1; e += 512){
    int2 rec = eb[e];
    int sl = ((unsigned)rec.x) >> 17;
    int pos = atomicAdd(&lcnt[sl], 1);
    ep[pos] = make_int2(rec.x & 0x1FFFF, rec.y);
  }
}

// ---------------- Gaussian table, fp16, nearest-neighbor (no lerp pair) ----------------
// Gth row r: 128 halves, [2c]=f-side, [2c+1]=s-side.  PRE-SCALED by log2(e):
// k_edge computes the gate in base-2 units; the ln2 factor on softplus cancels
// in the LayerNorm (scale-invariant), and sigmoid uses exp2 directly.
__global__ void k_gauss(const float* __restrict__ Wf, const float* __restrict__ bf,
                        const float* __restrict__ Ws, const float* __restrict__ bs,
                        __half* __restrict__ Gth){
  __shared__ float attr[64];
  int bi = blockIdx.x;                  // 3*TBL
  int i = bi / TBL, r = bi % TBL;
  int t = threadIdx.x;                  // 128
  float d = R_MIN_ + (R_MAX_-R_MIN_) * (float)r / (float)(TBL-1);
  if (t < 64){
    float cj = 1.f + 5.f * (float)t / 63.f;
    float u = (d - cj) * (64.f/5.f);
    attr[t] = __expf(-0.5f*u*u);
  }
  __syncthreads();
  int c = t >> 1;
  int side = t & 1;
  const float* W = (side ? Ws : Wf) + i*192*64 + 128*64 + c;
  float acc = (side ? bs : bf)[i*64 + c];
  #pragma unroll 8
  for (int j = 0; j < 64; j++) acc = fmaf(attr[j], W[j*64], acc);
  Gth[((size_t)i*TBL + r)*128 + t] = __float2half_rn(acc * LOG2E);
}

// ---------------- Wcat pack ----------------
__global__ void k_wcat(const float* __restrict__ Wf, const float* __restrict__ Ws,
                       float* __restrict__ Wcat){
  int idx = blockIdx.x*256 + threadIdx.x;
  if (idx >= 3*64*256) return;
  int i = idx / (64*256);
  int rem = idx % (64*256);
  int k = rem / 256, c = rem % 256;
  float v;
  if (c < 128){
    int p = c >> 1; bool ss = (c & 1);
    v = (ss ? Ws : Wf)[i*192*64 + k*64 + p];
  } else {
    int p = (c-128) >> 1; bool ss = (c & 1);
    v = (ss ? Ws : Wf)[i*192*64 + (64+k)*64 + p];
  }
  Wcat[i*64*256 + k*256 + c] = v;
}

// ---------------- node transform: 32 nodes x 256 cols; p and q stored fp16 ----------------
// Output pre-scaled by log2(e) (see k_gauss comment).
__global__ void k_ntrans(const float* __restrict__ x, const float* __restrict__ Wc,
                         __half2* __restrict__ pqh){
  __shared__ float xs[32*64];       // 8 KB
  int n0 = blockIdx.x * 32;         // 3125 blocks exact
  int t = threadIdx.x;              // 256
  ((float4*)xs)[t]       = ((const float4*)(x + (size_t)n0*64))[t];
  ((float4*)xs)[t + 256] = ((const float4*)(x + (size_t)n0*64))[t + 256];
  __syncthreads();
  int cg = t & 63, ng = t >> 6;     // 64 col-groups x 4 cols; 4 node-groups x 8 nodes
  float4 acc[8];
  #pragma unroll
  for (int i = 0; i < 8; i++) acc[i] = make_float4(0.f,0.f,0.f,0.f);
  const float* wp = Wc + 4*cg;
  const float* xp = xs + ng*8*64;
  #pragma unroll 2
  for (int k = 0; k < 64; k += 4){
    float4 w0 = *(const float4*)(wp + (k+0)*256);
    float4 w1 = *(const float4*)(wp + (k+1)*256);
    float4 w2 = *(const float4*)(wp + (k+2)*256);
    float4 w3 = *(const float4*)(wp + (k+3)*256);
    #pragma unroll
    for (int nn = 0; nn < 8; nn++){
      float4 xv = *(const float4*)(xp + nn*64 + k);
      fma4(acc[nn], xv.x, w0); fma4(acc[nn], xv.y, w1);
      fma4(acc[nn], xv.z, w2); fma4(acc[nn], xv.w, w3);
    }
  }
  #pragma unroll
  for (int nn = 0; nn < 8; nn++){
    int node = n0 + ng*8 + nn;
    __half2 h0 = __float22half2_rn(make_float2(acc[nn].x*LOG2E, acc[nn].y*LOG2E));
    __half2 h1 = __float22half2_rn(make_float2(acc[nn].z*LOG2E, acc[nn].w*LOG2E));
    __half2* dst = pqh + (size_t)node*128 + 2*cg;
    dst[0] = h0; dst[1] = h1;
  }
}

// ---------------- edge pass: wave per node, NN table, 2 loads/edge ----------------
// All inputs pre-scaled by log2(e):
//   sigmoid(z)        = rcp(1 + 2^(-p') * 2^(-(q'+g')))   (Cf = 2^(-p') hoisted per node)
//   softplus(z)/ln2   = max(z',0) + log2(1 + 2^(-|z'|))   (ln2 cancels in the LN)
// q+g summed packed fp16 (one v_pk_add_f16); 32-bit byte-offset gathers.
__global__ void k_edge(const __half2* __restrict__ pqh,
                       const int* __restrict__ offs, const int2* __restrict__ ep,
                       const __half* __restrict__ Gth, const float* __restrict__ lng,
                       const float* __restrict__ lnb, float* __restrict__ x){
  int wid  = (blockIdx.x*256 + threadIdx.x) >> 6;
  int lane = threadIdx.x & 63;
  int n = wid;
  int j0 = __builtin_amdgcn_readfirstlane(offs[n]);
  int j1 = __builtin_amdgcn_readfirstlane(offs[n+1]);
  int nfull = (j1 - j0) >> 3;
  int2 eb8[8];
  if (nfull > 0){
    #pragma unroll
    for (int i = 0; i < 8; i++) eb8[i] = ep[j0 + i];
  }
  float2 pp = __half22float2(pqh[(size_t)n*128 + lane]);
  float Cf = __builtin_amdgcn_exp2f(-pp.x);   // 2^(-p'_f), hoisted out of edge loop
  float ps = pp.y;
  const char* pqb = (const char*)pqh;
  const char* gtb = (const char*)Gth;
  unsigned qob = 256u + ((unsigned)lane << 2);  // byte off of q[lane] within a node row
  unsigned lob = (unsigned)lane << 2;           // byte off of g[lane] within a table row
  float acc = 0.f;
  int u = j0;
  for (int b = 0; b < nfull; b++){
    __half2 qr[8], gr[8];
    #pragma unroll
    for (int i = 0; i < 8; i++){
      qr[i] = *(const __half2*)(pqb + ((((unsigned)eb8[i].x) << 9) + qob));
      gr[i] = *(const __half2*)(gtb + ((((unsigned)eb8[i].y) << 8) + lob));
    }
    if (b + 1 < nfull){
      #pragma unroll
      for (int i = 0; i < 8; i++) eb8[i] = ep[u + 8 + i];
    }
    #pragma unroll
    for (int i = 0; i < 8; i++){
      float2 z = __half22float2(__hadd2(qr[i], gr[i]));
      float sig = __builtin_amdgcn_rcpf(fmaf(Cf, __builtin_amdgcn_exp2f(-z.x), 1.f));
      float zs = ps + z.y;
      float sp = fmaxf(zs, 0.f)
               + __builtin_amdgcn_logf(1.f + __builtin_amdgcn_exp2f(-fabsf(zs)));
      acc = fmaf(sig, sp, acc);
    }
    u += 8;
  }
  for (; u < j1; u++){
    int2 e = ep[u];
    __half2 q = *(const __half2*)(pqb + ((((unsigned)e.x) << 9) + qob));
    __half2 g = *(const __half2*)(gtb + ((((unsigned)e.y) << 8) + lob));
    float2 z = __half22float2(__hadd2(q, g));
    float sig = __builtin_amdgcn_rcpf(fmaf(Cf, __builtin_amdgcn_exp2f(-z.x), 1.f));
    float zs = ps + z.y;
    float sp = fmaxf(zs, 0.f)
             + __builtin_amdgcn_logf(1.f + __builtin_amdgcn_exp2f(-fabsf(zs)));
    acc = fmaf(sig, sp, acc);
  }
  // LN over 64 channels: scale-invariant, so the global ln2 factor on acc cancels
  float s1 = acc, s2 = acc*acc;
  #pragma unroll
  for (int o = 32; o > 0; o >>= 1){ s1 += __shfl_xor(s1, o, 64); s2 += __shfl_xor(s2, o, 64); }
  float mu  = s1 * (1.f/64.f);
  float var = s2 * (1.f/64.f) - mu*mu;
  float inv = rsqrtf(fmaxf(var, 0.f) + 1e-5f);
  float y = (acc - mu) * inv * lng[lane] + lnb[lane];
  x[(size_t)n*64 + lane] += y;
}

// ---------------- fused head with K=8 register-prefetched weights ----------------
__global__ void k_head(const float* __restrict__ x,
                       const float* __restrict__ W1, const float* __restrict__ b1,
                       const float* __restrict__ g1, const float* __restrict__ bt1,
                       const float* __restrict__ W2, const float* __restrict__ b2,
                       const float* __restrict__ g2, const float* __restrict__ bt2,
                       const float* __restrict__ Wout, const int* __restrict__ batch,
                       float* gsum, int* gcnt){
  __shared__ float xs[32*64];       // 8 KB
  __shared__ float hs[32*128];      // 16 KB
  __shared__ float es[32];
  int n0 = blockIdx.x * 32;         // 3125 blocks
  int t = threadIdx.x;              // 256
  ((float4*)xs)[t]       = ((const float4*)(x + (size_t)n0*64))[t];
  ((float4*)xs)[t + 256] = ((const float4*)(x + (size_t)n0*64))[t + 256];
  __syncthreads();
  int cg = t & 31, ng = t >> 5;     // 32 col-groups x 4 cols; 8 node-groups x 4 nodes

  // ---- layer 1: 64 -> 128, LN, softplus, into hs ----
  {
    float4 acc[4];
    #pragma unroll
    for (int i = 0; i < 4; i++) acc[i] = make_float4(0.f,0.f,0.f,0.f);
    const float* wp = W1 + 4*cg;
    const float* xp = xs + ng*4*64;
    float4 w[8];
    #pragma unroll
    for (int j = 0; j < 8; j++) w[j] = *(const float4*)(wp + j*128);
    for (int k = 0; k < 64; k += 8){
      float4 wn[8];
      int kn = (k + 8 < 64) ? k + 8 : 0;
      #pragma unroll
      for (int j = 0; j < 8; j++) wn[j] = *(const float4*)(wp + (kn+j)*128);
      #pragma unroll
      for (int h = 0; h < 2; h++){
        #pragma unroll
        for (int nn = 0; nn < 4; nn++){
          float4 xv = *(const float4*)(xp + nn*64 + k + h*4);
          fma4(acc[nn], xv.x, w[h*4+0]); fma4(acc[nn], xv.y, w[h*4+1]);
          fma4(acc[nn], xv.z, w[h*4+2]); fma4(acc[nn], xv.w, w[h*4+3]);
        }
      }
      #pragma unroll
      for (int j = 0; j < 8; j++) w[j] = wn[j];
    }
    float4 bv  = *(const float4*)(b1  + 4*cg);
    float4 gv  = *(const float4*)(g1  + 4*cg);
    float4 btv = *(const float4*)(bt1 + 4*cg);
    #pragma unroll
    for (int nn = 0; nn < 4; nn++){
      float4 v = acc[nn];
      v.x += bv.x; v.y += bv.y; v.z += bv.z; v.w += bv.w;
      float s1 = v.x + v.y + v.z + v.w;
      float s2 = v.x*v.x + v.y*v.y + v.z*v.z + v.w*v.w;
      #pragma unroll
      for (int o = 16; o > 0; o >>= 1){ s1 += __shfl_xor(s1, o, 64); s2 += __shfl_xor(s2, o, 64); }
      float mu  = s1 * (1.f/128.f);
      float var = s2 * (1.f/128.f) - mu*mu;
      float inv = rsqrtf(fmaxf(var, 0.f) + 1e-5f);
      float4 o4;
      o4.x = softplus_f((v.x - mu)*inv*gv.x + btv.x);
      o4.y = softplus_f((v.y - mu)*inv*gv.y + btv.y);
      o4.z = softplus_f((v.z - mu)*inv*gv.z + btv.z);
      o4.w = softplus_f((v.w - mu)*inv*gv.w + btv.w);
      *(float4*)(hs + (ng*4 + nn)*128 + 4*cg) = o4;
    }
  }
  __syncthreads();

  // ---- layer 2: 128 -> 128, LN, softplus, proj -> per-node energy in es ----
  {
    float4 acc[4];
    #pragma unroll
    for (int i = 0; i < 4; i++) acc[i] = make_float4(0.f,0.f,0.f,0.f);
    const float* wp = W2 + 4*cg;
    const float* hp = hs + ng*4*128;
    float4 w[8];
    #pragma unroll
    for (int j = 0; j < 8; j++) w[j] = *(const float4*)(wp + j*128);
    for (int k = 0; k < 128; k += 8){
      float4 wn[8];
      int kn = (k + 8 < 128) ? k + 8 : 0;
      #pragma unroll
      for (int j = 0; j < 8; j++) wn[j] = *(const float4*)(wp + (kn+j)*128);
      #pragma unroll
      for (int h = 0; h < 2; h++){
        #pragma unroll
        for (int nn = 0; nn < 4; nn++){
          float4 hv = *(const float4*)(hp + nn*128 + k + h*4);
          fma4(acc[nn], hv.x, w[h*4+0]); fma4(acc[nn], hv.y, w[h*4+1]);
          fma4(acc[nn], hv.z, w[h*4+2]); fma4(acc[nn], hv.w, w[h*4+3]);
        }
      }
      #pragma unroll
      for (int j = 0; j < 8; j++) w[j] = wn[j];
    }
    float4 bv  = *(const float4*)(b2  + 4*cg);
    float4 gv  = *(const float4*)(g2  + 4*cg);
    float4 btv = *(const float4*)(bt2 + 4*cg);
    float4 wo  = *(const float4*)(Wout + 4*cg);
    #pragma unroll
    for (int nn = 0; nn < 4; nn++){
      float4 v = acc[nn];
      v.x += bv.x; v.y += bv.y; v.z += bv.z; v.w += bv.w;
      float s1 = v.x + v.y + v.z + v.w;
      float s2 = v.x*v.x + v.y*v.y + v.z*v.z + v.w*v.w;
      #pragma unroll
      for (int o = 16; o > 0; o >>= 1){ s1 += __shfl_xor(s1, o, 64); s2 += __shfl_xor(s2, o, 64); }
      float mu  = s1 * (1.f/128.f);
      float var = s2 * (1.f/128.f) - mu*mu;
      float inv = rsqrtf(fmaxf(var, 0.f) + 1e-5f);
      float ev = softplus_f((v.x - mu)*inv*gv.x + btv.x) * wo.x
               + softplus_f((v.y - mu)*inv*gv.y + btv.y) * wo.y
               + softplus_f((v.z - mu)*inv*gv.z + btv.z) * wo.z
               + softplus_f((v.w - mu)*inv*gv.w + btv.w) * wo.w;
      #pragma unroll
      for (int o = 16; o > 0; o >>= 1) ev += __shfl_xor(ev, o, 64);
      if (cg == 0) es[ng*4 + nn] = ev;
    }
  }
  __syncthreads();

  // ---- segmented reduction over the sorted 32-node tile ----
  if (t < 32){
    int node = n0 + t;
    int g = batch[node];
    bool head = (t == 0) || (batch[node-1] != g);
    if (head){
      float s = 0.f; int c = 0;
      int j = t;
      while (j < 32 && batch[n0+j] == g){ s += es[j]; c++; j++; }
      atomicAdd(&gsum[g], s);
      atomicAdd(&gcnt[g], c);
    }
  }
}

// ---------------- final ----------------
__global__ void k_final(const float* __restrict__ gsum, const int* __restrict__ gcnt,
                        const float* __restrict__ bout, float* __restrict__ out){
  int g = threadIdx.x;
  if (g < NGRAPH)
    out[g] = gsum[g] / fmaxf((float)gcnt[g], 1.f) + bout[0];
}

extern "C" void kernel_launch(void* const* d_in, const int* in_sizes, int n_in,
                              void* d_out, int out_size, void* d_ws, size_t ws_size,
                              hipStream_t stream){
  const int*   numbers = (const int*)d_in[0];
  const int*   eidx    = (const int*)d_in[1];
  const float* elen    = (const float*)d_in[2];
  const int*   batch   = (const int*)d_in[3];
  const float* embed   = (const float*)d_in[4];
  const float* Wf      = (const float*)d_in[5];
  const float* bf      = (const float*)d_in[6];
  const float* Ws      = (const float*)d_in[7];
  const float* bs      = (const float*)d_in[8];
  const float* lng     = (const float*)d_in[9];
  const float* lnb     = (const float*)d_in[10];
  const float* W1      = (const float*)d_in[11];
  const float* b1      = (const float*)d_in[12];
  const float* g1      = (const float*)d_in[13];
  const float* bt1     = (const float*)d_in[14];
  const float* W2      = (const float*)d_in[15];
  const float* b2      = (const float*)d_in[16];
  const float* g2      = (const float*)d_in[17];
  const float* bt2     = (const float*)d_in[18];
  const float* Wout    = (const float*)d_in[19];
  const float* bout    = (const float*)d_in[20];
  const int* src = eidx;
  const int* tgt = eidx + NEDGES;

  float*   x    = (float*)d_ws;                          // N*64 f32
  __half2* pqh  = (__half2*)(x + (size_t)NNODES*64);     // N*128 half2
  __half*  Gth  = (__half*)(pqh + (size_t)NNODES*128);   // 3*TBL*128 half
  float*   Wcat = (float*)(Gth + (size_t)3*TBL*128);     // 3*64*256 f32
  int2*    ep   = (int2*)(Wcat + (size_t)3*64*256);      // E int2 (final CSR)
  int2*    ebuf = ep + NEDGES;                           // E int2 (staging)
  int*     offs = (int*)(ebuf + NEDGES);                 // N+1
  int*     ccnt = offs + NNODES + 1;                     // 256
  int*     cbase= ccnt + 256;                            // 256 (197 used)
  int*     ccur = cbase + 256;                           // 256
  float*   gsum = (float*)(ccur + 256);                  // 256
  int*     gcnt = (int*)(gsum + NGRAPH);                 // 256
  float*   out  = (float*)d_out;

  k_init  <<<(NNODES+255)/256, 256, 0, stream>>>(ccnt, gsum, gcnt);
  k_embed <<<(NNODES*64+255)/256, 256, 0, stream>>>(numbers, embed, x);

  k_cnt   <<<(NEDGES+2047)/2048, 256, 0, stream>>>(src, ccnt);
  k_cscan <<<1, 256, 0, stream>>>(ccnt, cbase, ccur, offs);
  k_bin   <<<(NEDGES+2047)/2048, 256, 0, stream>>>(src, tgt, elen, ccur, ebuf);
  k_fine  <<<NCHUNK, 512, 0, stream>>>(cbase, ebuf, ep, offs);

  k_gauss <<<3*TBL, 128, 0, stream>>>(Wf, bf, Ws, bs, Gth);
  k_wcat  <<<(3*64*256+255)/256, 256, 0, stream>>>(Wf, Ws, Wcat);

  for (int i = 0; i < NCONV; i++){
    k_ntrans<<<NNODES/32, 256, 0, stream>>>(x, Wcat + (size_t)i*64*256, pqh);
    k_edge  <<<NNODES/4, 256, 0, stream>>>(pqh, offs, ep,
                                           Gth + (size_t)i*TBL*128,
                                           lng + i*64, lnb + i*64, x);
  }

  k_head<<<NNODES/32, 256, 0, stream>>>(x, W1, b1, g1, bt1,
                                        W2, b2, g2, bt2, Wout, batch, gsum, gcnt);
  k_final<<<1, 256, 0, stream>>>(gsum, gcnt, bout, out);
}

// Round 2
// 654.442 us; speedup vs baseline: 1.2286x; 1.0834x over previous
//
#include <hip/hip_runtime.h>
#include <hip/hip_fp16.h>
#include <math.h>

#define NNODES 100000
#define NEDGES 1600000
#define NGRAPH 256
#define NCONV  3
#define TBL    4096
#define CHUNK  512
#define NCHUNK 196         // ceil(100000/512)
#define R_MIN_ 1.0f
#define R_MAX_ 6.0f
#define LOG2E  1.4426950408889634f

typedef _Float16 h2t __attribute__((ext_vector_type(2)));
union H4 { float4 f4; __half2 q[4]; h2t h[4]; };

__device__ __forceinline__ float softplus_f(float x){
  return fmaxf(x, 0.f) + __logf(1.f + __expf(-fabsf(x)));
}
__device__ __forceinline__ void fma4(float4& a, float s, const float4 w){
  a.x = fmaf(s, w.x, a.x); a.y = fmaf(s, w.y, a.y);
  a.z = fmaf(s, w.z, a.z); a.w = fmaf(s, w.w, a.w);
}

// ---------------- init: zero chunk counters + graph accumulators ----------------
__global__ void k_init(int* ccnt, float* gsum, int* gcnt){
  int i = blockIdx.x*256 + threadIdx.x;
  if (i < 256) ccnt[i] = 0;
  if (i < NGRAPH){ gsum[i] = 0.f; gcnt[i] = 0; }
}

// ---------------- embedding gather ----------------
__global__ void k_embed(const int* __restrict__ numbers, const float* __restrict__ embed,
                        float* __restrict__ x){
  int i = blockIdx.x*256 + threadIdx.x;
  if (i >= NNODES*64) return;
  int n = i >> 6, c = i & 63;
  x[i] = embed[numbers[n]*64 + c];
}

// ---------------- chunk count: LDS histogram then 196 global atomics per block ----------------
__global__ void k_cnt(const int* __restrict__ src, int* ccnt){
  __shared__ int l[NCHUNK];
  int t = threadIdx.x;
  int e0 = blockIdx.x * 2048;
  if (t < NCHUNK) l[t] = 0;
  __syncthreads();
  #pragma unroll
  for (int k = 0; k < 8; k++){
    int e = e0 + k*256 + t;
    if (e < NEDGES) atomicAdd(&l[src[e] / CHUNK], 1);
  }
  __syncthreads();
  if (t < NCHUNK && l[t] > 0) atomicAdd(&ccnt[t], l[t]);
}

// ---------------- chunk scan: cbase prefix, init ccur, sentinel ----------------
__global__ void k_cscan(const int* __restrict__ ccnt, int* __restrict__ cbase,
                        int* __restrict__ ccur, int* __restrict__ offs){
  int t = threadIdx.x;
  if (t == 0){
    int run = 0;
    for (int c = 0; c < NCHUNK; c++){ cbase[c] = run; run += ccnt[c]; }
    cbase[NCHUNK] = NEDGES;
    offs[NNODES] = NEDGES;
  }
  __syncthreads();
  if (t < NCHUNK) ccur[t] = cbase[t];
}

// ---------------- pass 1: bin edges by 512-node chunk ----------------
// staged record: .x = (src&511)<<17 | tgt ; .y = nearest-neighbor table idx
__global__ void k_bin(const int* __restrict__ src, const int* __restrict__ tgt,
                      const float* __restrict__ elen, int* ccur,
                      int2* __restrict__ eb){
  __shared__ int lcnt[NCHUNK];
  __shared__ int lbase[NCHUNK];
  __shared__ int loff[NCHUNK];
  int t = threadIdx.x;
  int e0 = blockIdx.x * 2048;
  if (t < NCHUNK){ lcnt[t] = 0; loff[t] = 0; }
  __syncthreads();
  #pragma unroll
  for (int k = 0; k < 8; k++){
    int e = e0 + k*256 + t;
    if (e < NEDGES) atomicAdd(&lcnt[src[e] / CHUNK], 1);
  }
  __syncthreads();
  if (t < NCHUNK && lcnt[t] > 0) lbase[t] = atomicAdd(&ccur[t], lcnt[t]);
  __syncthreads();
  #pragma unroll
  for (int k = 0; k < 8; k++){
    int e = e0 + k*256 + t;
    if (e < NEDGES){
      int s = src[e];
      int c = s / CHUNK;
      int r = atomicAdd(&loff[c], 1);
      float key = (elen[e] - R_MIN_) * ((float)(TBL-1)/(R_MAX_-R_MIN_));
      key = fmaxf(key, 0.f);
      int idx = (int)(key + 0.5f);
      if (idx > TBL-1) idx = TBL-1;
      eb[lbase[c] + r] = make_int2(((s & (CHUNK-1)) << 17) | tgt[e], idx);
    }
  }
}

// ---------------- pass 2: fine scatter; also builds offs via LDS count+scan ----------------
__global__ void k_fine(const int* __restrict__ cbase, const int2* __restrict__ eb,
                       int2* __restrict__ ep, int* __restrict__ offs){
  __shared__ int lcnt[CHUNK];
  __shared__ int lsc[CHUNK];
  int c = blockIdx.x;
  int t = threadIdx.x;                    // 512 threads
  int n0 = c * CHUNK;
  int n1 = min(n0 + CHUNK, NNODES);
  int cnt = n1 - n0;
  int j0 = cbase[c], j1 = cbase[c+1];
  lcnt[t] = 0;
  __syncthreads();
  for (int e = j0 + t; e < j1; e += 512)
    atomicAdd(&lcnt[((unsigned)eb[e].x) >> 17], 1);
  __syncthreads();
  lsc[t] = lcnt[t];
  __syncthreads();
  for (int d = 1; d < 512; d <<= 1){
    int v = (t >= d) ? lsc[t-d] : 0;
    __syncthreads();
    lsc[t] += v;
    __syncthreads();
  }
  int excl = lsc[t] - lcnt[t];
  if (t < cnt) offs[n0 + t] = j0 + excl;
  __syncthreads();
  lcnt[t] = j0 + excl;                    // reuse as cursors
  __syncthreads();
  for (int e = j0 + t; e < j1; e += 512){
    int2 rec = eb[e];
    int sl = ((unsigned)rec.x) >> 17;
    int pos = atomicAdd(&lcnt[sl], 1);
    ep[pos] = make_int2(rec.x & 0x1FFFF, rec.y);
  }
}

// ---------------- Gaussian table, fp16, nearest-neighbor (no lerp pair) ----------------
// Gth row r: 128 halves, [2c]=f-side, [2c+1]=s-side.  PRE-SCALED by log2(e).
__global__ void k_gauss(const float* __restrict__ Wf, const float* __restrict__ bf,
                        const float* __restrict__ Ws, const float* __restrict__ bs,
                        __half* __restrict__ Gth){
  __shared__ float attr[64];
  int bi = blockIdx.x;                  // 3*TBL
  int i = bi / TBL, r = bi % TBL;
  int t = threadIdx.x;                  // 128
  float d = R_MIN_ + (R_MAX_-R_MIN_) * (float)r / (float)(TBL-1);
  if (t < 64){
    float cj = 1.f + 5.f * (float)t / 63.f;
    float u = (d - cj) * (64.f/5.f);
    attr[t] = __expf(-0.5f*u*u);
  }
  __syncthreads();
  int c = t >> 1;
  int side = t & 1;
  const float* W = (side ? Ws : Wf) + i*192*64 + 128*64 + c;
  float acc = (side ? bs : bf)[i*64 + c];
  #pragma unroll 8
  for (int j = 0; j < 64; j++) acc = fmaf(attr[j], W[j*64], acc);
  Gth[((size_t)i*TBL + r)*128 + t] = __float2half_rn(acc * LOG2E);
}

// ---------------- Wcat pack: half2 k-pairs, [i][kp(32)][c(256)] ----------------
__global__ void k_wcat(const float* __restrict__ Wf, const float* __restrict__ Ws,
                       __half2* __restrict__ Wch){
  int idx = blockIdx.x*256 + threadIdx.x;
  if (idx >= 3*32*256) return;
  int i = idx / (32*256);
  int rem = idx % (32*256);
  int kp = rem >> 8, c = rem & 255;
  int p = (c < 128) ? (c >> 1) : ((c - 128) >> 1);
  int rbase = (c < 128) ? 0 : 64;
  const float* W = ((c & 1) ? Ws : Wf) + i*192*64;
  float v0 = W[(rbase + 2*kp  )*64 + p];
  float v1 = W[(rbase + 2*kp+1)*64 + p];
  Wch[idx] = __floats2half2_rn(v0, v1);
}

// ---------------- head weight pack: half2 k-pairs, [kp][128] ----------------
__global__ void k_whalf(const float* __restrict__ W1, const float* __restrict__ W2,
                        __half2* __restrict__ Wh1, __half2* __restrict__ Wh2){
  int i = blockIdx.x*256 + threadIdx.x;
  if (i < 32*128){
    int kp = i >> 7, c = i & 127;
    Wh1[i] = __floats2half2_rn(W1[(2*kp)*128 + c], W1[(2*kp+1)*128 + c]);
  } else if (i < 32*128 + 64*128){
    int j = i - 32*128;
    int kp = j >> 7, c = j & 127;
    Wh2[j] = __floats2half2_rn(W2[(2*kp)*128 + c], W2[(2*kp+1)*128 + c]);
  }
}

// ---------------- node transform: fp16 dot2, 32 nodes x 256 cols ----------------
// Output pre-scaled by log2(e).
__global__ void k_ntrans(const float* __restrict__ x, const __half2* __restrict__ Wch,
                         __half2* __restrict__ pqh){
  __shared__ __half2 xh[32*32];     // 4 KB, [node][kp]
  int n0 = blockIdx.x * 32;         // 3125 blocks exact
  int t = threadIdx.x;              // 256
  {
    const float4* xp = (const float4*)(x + (size_t)n0*64);
    float4 a = xp[2*t], b = xp[2*t+1];
    H4 hh;
    hh.q[0] = __float22half2_rn(make_float2(a.x, a.y));
    hh.q[1] = __float22half2_rn(make_float2(a.z, a.w));
    hh.q[2] = __float22half2_rn(make_float2(b.x, b.y));
    hh.q[3] = __float22half2_rn(make_float2(b.z, b.w));
    *(float4*)(xh + 4*t) = hh.f4;
  }
  __syncthreads();
  int cg = t & 63, ng = t >> 6;     // 64 col-groups x 4 cols; 4 node-groups x 8 nodes
  float4 acc[8];
  #pragma unroll
  for (int i = 0; i < 8; i++) acc[i] = make_float4(0.f,0.f,0.f,0.f);
  const __half2* wp = Wch + 4*cg;
  const __half2* xbase = xh + ng*8*32;
  for (int kp = 0; kp < 32; kp += 4){
    H4 w[4];
    #pragma unroll
    for (int j = 0; j < 4; j++) w[j].f4 = *(const float4*)(wp + (kp+j)*256);
    #pragma unroll
    for (int nn = 0; nn < 8; nn++){
      H4 xv; xv.f4 = *(const float4*)(xbase + nn*32 + kp);
      #pragma unroll
      for (int j = 0; j < 4; j++){
        acc[nn].x = __builtin_amdgcn_fdot2(xv.h[j], w[j].h[0], acc[nn].x, false);
        acc[nn].y = __builtin_amdgcn_fdot2(xv.h[j], w[j].h[1], acc[nn].y, false);
        acc[nn].z = __builtin_amdgcn_fdot2(xv.h[j], w[j].h[2], acc[nn].z, false);
        acc[nn].w = __builtin_amdgcn_fdot2(xv.h[j], w[j].h[3], acc[nn].w, false);
      }
    }
  }
  #pragma unroll
  for (int nn = 0; nn < 8; nn++){
    int node = n0 + ng*8 + nn;
    __half2 h0 = __float22half2_rn(make_float2(acc[nn].x*LOG2E, acc[nn].y*LOG2E));
    __half2 h1 = __float22half2_rn(make_float2(acc[nn].z*LOG2E, acc[nn].w*LOG2E));
    __half2* dst = pqh + (size_t)node*128 + 2*cg;
    dst[0] = h0; dst[1] = h1;
  }
}

// ---------------- edge pass: wave per node, NN table, 2 loads/edge ----------------
__global__ void k_edge(const __half2* __restrict__ pqh,
                       const int* __restrict__ offs, const int2* __restrict__ ep,
                       const __half* __restrict__ Gth, const float* __restrict__ lng,
                       const float* __restrict__ lnb, float* __restrict__ x){
  int wid  = (blockIdx.x*256 + threadIdx.x) >> 6;
  int lane = threadIdx.x & 63;
  int n = wid;
  int j0 = __builtin_amdgcn_readfirstlane(offs[n]);
  int j1 = __builtin_amdgcn_readfirstlane(offs[n+1]);
  int nfull = (j1 - j0) >> 3;
  int2 eb8[8];
  if (nfull > 0){
    #pragma unroll
    for (int i = 0; i < 8; i++) eb8[i] = ep[j0 + i];
  }
  float2 pp = __half22float2(pqh[(size_t)n*128 + lane]);
  float Cf = __builtin_amdgcn_exp2f(-pp.x);   // 2^(-p'_f), hoisted out of edge loop
  float ps = pp.y;
  const char* pqb = (const char*)pqh;
  const char* gtb = (const char*)Gth;
  unsigned qob = 256u + ((unsigned)lane << 2);
  unsigned lob = (unsigned)lane << 2;
  float acc = 0.f;
  int u = j0;
  for (int b = 0; b < nfull; b++){
    __half2 qr[8], gr[8];
    #pragma unroll
    for (int i = 0; i < 8; i++){
      qr[i] = *(const __half2*)(pqb + ((((unsigned)eb8[i].x) << 9) + qob));
      gr[i] = *(const __half2*)(gtb + ((((unsigned)eb8[i].y) << 8) + lob));
    }
    if (b + 1 < nfull){
      #pragma unroll
      for (int i = 0; i < 8; i++) eb8[i] = ep[u + 8 + i];
    }
    #pragma unroll
    for (int i = 0; i < 8; i++){
      float2 z = __half22float2(__hadd2(qr[i], gr[i]));
      float sig = __builtin_amdgcn_rcpf(fmaf(Cf, __builtin_amdgcn_exp2f(-z.x), 1.f));
      float zs = ps + z.y;
      float sp = fmaxf(zs, 0.f)
               + __builtin_amdgcn_logf(1.f + __builtin_amdgcn_exp2f(-fabsf(zs)));
      acc = fmaf(sig, sp, acc);
    }
    u += 8;
  }
  for (; u < j1; u++){
    int2 e = ep[u];
    __half2 q = *(const __half2*)(pqb + ((((unsigned)e.x) << 9) + qob));
    __half2 g = *(const __half2*)(gtb + ((((unsigned)e.y) << 8) + lob));
    float2 z = __half22float2(__hadd2(q, g));
    float sig = __builtin_amdgcn_rcpf(fmaf(Cf, __builtin_amdgcn_exp2f(-z.x), 1.f));
    float zs = ps + z.y;
    float sp = fmaxf(zs, 0.f)
             + __builtin_amdgcn_logf(1.f + __builtin_amdgcn_exp2f(-fabsf(zs)));
    acc = fmaf(sig, sp, acc);
  }
  float s1 = acc, s2 = acc*acc;
  #pragma unroll
  for (int o = 32; o > 0; o >>= 1){ s1 += __shfl_xor(s1, o, 64); s2 += __shfl_xor(s2, o, 64); }
  float mu  = s1 * (1.f/64.f);
  float var = s2 * (1.f/64.f) - mu*mu;
  float inv = rsqrtf(fmaxf(var, 0.f) + 1e-5f);
  float y = (acc - mu) * inv * lng[lane] + lnb[lane];
  x[(size_t)n*64 + lane] += y;
}

// ---------------- fused head: fp16 dot2 GEMMs, fp16 LDS tiles ----------------
__global__ void k_head(const float* __restrict__ x,
                       const __half2* __restrict__ Wh1, const float* __restrict__ b1,
                       const float* __restrict__ g1, const float* __restrict__ bt1,
                       const __half2* __restrict__ Wh2, const float* __restrict__ b2,
                       const float* __restrict__ g2, const float* __restrict__ bt2,
                       const float* __restrict__ Wout, const int* __restrict__ batch,
                       float* gsum, int* gcnt){
  __shared__ __half2 xh[32*32];     // 4 KB  [node][kp]
  __shared__ __half2 hsh[32*64];    // 8 KB  [node][kp2]
  __shared__ float es[32];
  int n0 = blockIdx.x * 32;         // 3125 blocks
  int t = threadIdx.x;              // 256
  {
    const float4* xp = (const float4*)(x + (size_t)n0*64);
    float4 a = xp[2*t], b = xp[2*t+1];
    H4 hh;
    hh.q[0] = __float22half2_rn(make_float2(a.x, a.y));
    hh.q[1] = __float22half2_rn(make_float2(a.z, a.w));
    hh.q[2] = __float22half2_rn(make_float2(b.x, b.y));
    hh.q[3] = __float22half2_rn(make_float2(b.z, b.w));
    *(float4*)(xh + 4*t) = hh.f4;
  }
  __syncthreads();
  int cg = t & 31, ng = t >> 5;     // 32 col-groups x 4 cols; 8 node-groups x 4 nodes

  // ---- layer 1: 64 -> 128 (dot2), LN, softplus, into hsh (fp16) ----
  {
    float4 acc[4];
    #pragma unroll
    for (int i = 0; i < 4; i++) acc[i] = make_float4(0.f,0.f,0.f,0.f);
    const __half2* wp = Wh1 + 4*cg;
    const __half2* xp = xh + ng*4*32;
    for (int kp = 0; kp < 32; kp += 4){
      H4 w[4];
      #pragma unroll
      for (int j = 0; j < 4; j++) w[j].f4 = *(const float4*)(wp + (kp+j)*128);
      #pragma unroll
      for (int nn = 0; nn < 4; nn++){
        H4 xv; xv.f4 = *(const float4*)(xp + nn*32 + kp);
        #pragma unroll
        for (int j = 0; j < 4; j++){
          acc[nn].x = __builtin_amdgcn_fdot2(xv.h[j], w[j].h[0], acc[nn].x, false);
          acc[nn].y = __builtin_amdgcn_fdot2(xv.h[j], w[j].h[1], acc[nn].y, false);
          acc[nn].z = __builtin_amdgcn_fdot2(xv.h[j], w[j].h[2], acc[nn].z, false);
          acc[nn].w = __builtin_amdgcn_fdot2(xv.h[j], w[j].h[3], acc[nn].w, false);
        }
      }
    }
    float4 bv  = *(const float4*)(b1  + 4*cg);
    float4 gv  = *(const float4*)(g1  + 4*cg);
    float4 btv = *(const float4*)(bt1 + 4*cg);
    #pragma unroll
    for (int nn = 0; nn < 4; nn++){
      float4 v = acc[nn];
      v.x += bv.x; v.y += bv.y; v.z += bv.z; v.w += bv.w;
      float s1 = v.x + v.y + v.z + v.w;
      float s2 = v.x*v.x + v.y*v.y + v.z*v.z + v.w*v.w;
      #pragma unroll
      for (int o = 16; o > 0; o >>= 1){ s1 += __shfl_xor(s1, o, 64); s2 += __shfl_xor(s2, o, 64); }
      float mu  = s1 * (1.f/128.f);
      float var = s2 * (1.f/128.f) - mu*mu;
      float inv = rsqrtf(fmaxf(var, 0.f) + 1e-5f);
      float4 o4;
      o4.x = softplus_f((v.x - mu)*inv*gv.x + btv.x);
      o4.y = softplus_f((v.y - mu)*inv*gv.y + btv.y);
      o4.z = softplus_f((v.z - mu)*inv*gv.z + btv.z);
      o4.w = softplus_f((v.w - mu)*inv*gv.w + btv.w);
      __half2 p0 = __float22half2_rn(make_float2(o4.x, o4.y));
      __half2 p1 = __float22half2_rn(make_float2(o4.z, o4.w));
      __half2* dst = hsh + (ng*4 + nn)*64 + 2*cg;
      dst[0] = p0; dst[1] = p1;
    }
  }
  __syncthreads();

  // ---- layer 2: 128 -> 128 (dot2), LN, softplus, proj -> per-node energy ----
  {
    float4 acc[4];
    #pragma unroll
    for (int i = 0; i < 4; i++) acc[i] = make_float4(0.f,0.f,0.f,0.f);
    const __half2* wp = Wh2 + 4*cg;
    const __half2* hp = hsh + ng*4*64;
    for (int kp = 0; kp < 64; kp += 4){
      H4 w[4];
      #pragma unroll
      for (int j = 0; j < 4; j++) w[j].f4 = *(const float4*)(wp + (kp+j)*128);
      #pragma unroll
      for (int nn = 0; nn < 4; nn++){
        H4 hv; hv.f4 = *(const float4*)(hp + nn*64 + kp);
        #pragma unroll
        for (int j = 0; j < 4; j++){
          acc[nn].x = __builtin_amdgcn_fdot2(hv.h[j], w[j].h[0], acc[nn].x, false);
          acc[nn].y = __builtin_amdgcn_fdot2(hv.h[j], w[j].h[1], acc[nn].y, false);
          acc[nn].z = __builtin_amdgcn_fdot2(hv.h[j], w[j].h[2], acc[nn].z, false);
          acc[nn].w = __builtin_amdgcn_fdot2(hv.h[j], w[j].h[3], acc[nn].w, false);
        }
      }
    }
    float4 bv  = *(const float4*)(b2  + 4*cg);
    float4 gv  = *(const float4*)(g2  + 4*cg);
    float4 btv = *(const float4*)(bt2 + 4*cg);
    float4 wo  = *(const float4*)(Wout + 4*cg);
    #pragma unroll
    for (int nn = 0; nn < 4; nn++){
      float4 v = acc[nn];
      v.x += bv.x; v.y += bv.y; v.z += bv.z; v.w += bv.w;
      float s1 = v.x + v.y + v.z + v.w;
      float s2 = v.x*v.x + v.y*v.y + v.z*v.z + v.w*v.w;
      #pragma unroll
      for (int o = 16; o > 0; o >>= 1){ s1 += __shfl_xor(s1, o, 64); s2 += __shfl_xor(s2, o, 64); }
      float mu  = s1 * (1.f/128.f);
      float var = s2 * (1.f/128.f) - mu*mu;
      float inv = rsqrtf(fmaxf(var, 0.f) + 1e-5f);
      float ev = softplus_f((v.x - mu)*inv*gv.x + btv.x) * wo.x
               + softplus_f((v.y - mu)*inv*gv.y + btv.y) * wo.y
               + softplus_f((v.z - mu)*inv*gv.z + btv.z) * wo.z
               + softplus_f((v.w - mu)*inv*gv.w + btv.w) * wo.w;
      #pragma unroll
      for (int o = 16; o > 0; o >>= 1) ev += __shfl_xor(ev, o, 64);
      if (cg == 0) es[ng*4 + nn] = ev;
    }
  }
  __syncthreads();

  // ---- segmented reduction over the sorted 32-node tile ----
  if (t < 32){
    int node = n0 + t;
    int g = batch[node];
    bool head = (t == 0) || (batch[node-1] != g);
    if (head){
      float s = 0.f; int c = 0;
      int j = t;
      while (j < 32 && batch[n0+j] == g){ s += es[j]; c++; j++; }
      atomicAdd(&gsum[g], s);
      atomicAdd(&gcnt[g], c);
    }
  }
}

// ---------------- final ----------------
__global__ void k_final(const float* __restrict__ gsum, const int* __restrict__ gcnt,
                        const float* __restrict__ bout, float* __restrict__ out){
  int g = threadIdx.x;
  if (g < NGRAPH)
    out[g] = gsum[g] / fmaxf((float)gcnt[g], 1.f) + bout[0];
}

extern "C" void kernel_launch(void* const* d_in, const int* in_sizes, int n_in,
                              void* d_out, int out_size, void* d_ws, size_t ws_size,
                              hipStream_t stream){
  const int*   numbers = (const int*)d_in[0];
  const int*   eidx    = (const int*)d_in[1];
  const float* elen    = (const float*)d_in[2];
  const int*   batch   = (const int*)d_in[3];
  const float* embed   = (const float*)d_in[4];
  const float* Wf      = (const float*)d_in[5];
  const float* bf      = (const float*)d_in[6];
  const float* Ws      = (const float*)d_in[7];
  const float* bs      = (const float*)d_in[8];
  const float* lng     = (const float*)d_in[9];
  const float* lnb     = (const float*)d_in[10];
  const float* W1      = (const float*)d_in[11];
  const float* b1      = (const float*)d_in[12];
  const float* g1      = (const float*)d_in[13];
  const float* bt1     = (const float*)d_in[14];
  const float* W2      = (const float*)d_in[15];
  const float* b2      = (const float*)d_in[16];
  const float* g2      = (const float*)d_in[17];
  const float* bt2     = (const float*)d_in[18];
  const float* Wout    = (const float*)d_in[19];
  const float* bout    = (const float*)d_in[20];
  const int* src = eidx;
  const int* tgt = eidx + NEDGES;

  float*   x    = (float*)d_ws;                          // N*64 f32
  __half2* pqh  = (__half2*)(x + (size_t)NNODES*64);     // N*128 half2
  __half*  Gth  = (__half*)(pqh + (size_t)NNODES*128);   // 3*TBL*128 half
  __half2* Wch  = (__half2*)(Gth + (size_t)3*TBL*128);   // 3*32*256 half2
  __half2* Wh1  = Wch + (size_t)3*32*256;                // 32*128 half2
  __half2* Wh2  = Wh1 + (size_t)32*128;                  // 64*128 half2
  int2*    ep   = (int2*)(Wh2 + (size_t)64*128);         // E int2 (final CSR)
  int2*    ebuf = ep + NEDGES;                           // E int2 (staging)
  int*     offs = (int*)(ebuf + NEDGES);                 // N+1
  int*     ccnt = offs + NNODES + 1;                     // 256
  int*     cbase= ccnt + 256;                            // 256 (197 used)
  int*     ccur = cbase + 256;                           // 256
  float*   gsum = (float*)(ccur + 256);                  // 256
  int*     gcnt = (int*)(gsum + NGRAPH);                 // 256
  float*   out  = (float*)d_out;

  k_init  <<<(NNODES+255)/256, 256, 0, stream>>>(ccnt, gsum, gcnt);
  k_embed <<<(NNODES*64+255)/256, 256, 0, stream>>>(numbers, embed, x);

  k_cnt   <<<(NEDGES+2047)/2048, 256, 0, stream>>>(src, ccnt);
  k_cscan <<<1, 256, 0, stream>>>(ccnt, cbase, ccur, offs);
  k_bin   <<<(NEDGES+2047)/2048, 256, 0, stream>>>(src, tgt, elen, ccur, ebuf);
  k_fine  <<<NCHUNK, 512, 0, stream>>>(cbase, ebuf, ep, offs);

  k_gauss <<<3*TBL, 128, 0, stream>>>(Wf, bf, Ws, bs, Gth);
  k_wcat  <<<(3*32*256+255)/256, 256, 0, stream>>>(Wf, Ws, Wch);
  k_whalf <<<(32*128+64*128+255)/256, 256, 0, stream>>>(W1, W2, Wh1, Wh2);

  for (int i = 0; i < NCONV; i++){
    k_ntrans<<<NNODES/32, 256, 0, stream>>>(x, Wch + (size_t)i*32*256, pqh);
    k_edge  <<<NNODES/4, 256, 0, stream>>>(pqh, offs, ep,
                                           Gth + (size_t)i*TBL*128,
                                           lng + i*64, lnb + i*64, x);
  }

  k_head<<<NNODES/32, 256, 0, stream>>>(x, Wh1, b1, g1, bt1,
                                        Wh2, b2, g2, bt2, Wout, batch, gsum, gcnt);
  k_final<<<1, 256, 0, stream>>>(gsum, gcnt, bout, out);
}